// Round 13
// baseline (195.462 us; speedup 1.0000x reference)
//
#include <hip/hip_runtime.h>
#include <hip/hip_bf16.h>

#define B_SZ 4096
#define N_SZ 200

// workspace offsets (4-byte units)
#define OFF_BFRAG 0        // 12288 u32: W-fragments, 3 layers x 2kt x 4ct x 2(hi/lo) x 64 lanes x 4 u32
#define OFF_AW1BT 12288    // 4096 f32: aw1bT[d][k] = att_w1[k][64+d]  (for qc prep)
#define OFF_ERC   16384    // 384  f32: erc[r][k]
#define OFF_QC    16768    // B*64 f32: qc[b][k]
#define OFF_AGG   278912   // B*64 f32: unnormalized sum miu*f (atomic)
#define OFF_SC    541056   // B    f32: sum miu (atomic)
// total 545152 floats = 2.18 MB

typedef __attribute__((ext_vector_type(8))) __bf16 bf16x8;
typedef __attribute__((ext_vector_type(4))) __bf16 bf16x4;
typedef __attribute__((ext_vector_type(4))) float f32x4;
typedef __attribute__((ext_vector_type(4))) unsigned u32x4;

__device__ __forceinline__ void split2(float x, unsigned &hi, unsigned &lo) {
    unsigned u = __float_as_uint(x);
    hi = (u + 0x7FFFu + ((u >> 16) & 1u)) >> 16;
    float r = x - __uint_as_float(hi << 16);
    unsigned ul = __float_as_uint(r);
    lo = (ul + 0x7FFFu + ((ul >> 16) & 1u)) >> 16;
}

// ---------- prep (unchanged, proven) ----------
__global__ void prep1(const float* __restrict__ gu_w1, const float* __restrict__ gu_b1,
                      const float* __restrict__ gu_w2, const float* __restrict__ att_w1,
                      const float* __restrict__ rate_emb, float* __restrict__ ws) {
    int t = threadIdx.x;  // 1 block x 256
    unsigned* wsu = (unsigned*)ws;
    for (int i = t; i < 12288; i += 256) {
        int frag = i >> 8, within = i & 255, lane = within >> 2, r = within & 3;
        int hl = frag & 1, ct = (frag >> 1) & 3, kt = (frag >> 3) & 1, layer = frag >> 4;
        int col = ct * 16 + (lane & 15);
        int d0 = kt * 32 + 8 * (lane >> 4) + 2 * r;
        float w0, w1v;
        if (layer == 0)      { w0 = gu_w1[col * 128 + d0];  w1v = gu_w1[col * 128 + d0 + 1]; }
        else if (layer == 1) { w0 = gu_w2[col * 64 + d0];   w1v = gu_w2[col * 64 + d0 + 1]; }
        else                 { w0 = att_w1[col * 128 + d0]; w1v = att_w1[col * 128 + d0 + 1]; }
        unsigned h0, l0, h1, l1;
        split2(w0, h0, l0); split2(w1v, h1, l1);
        unsigned lo16 = hl ? l0 : h0;
        unsigned hi16 = hl ? l1 : h1;
        wsu[OFF_BFRAG + i] = lo16 | (hi16 << 16);
    }
    for (int i = t; i < 4096; i += 256) {
        int d = i >> 6, k = i & 63;
        ws[OFF_AW1BT + i] = att_w1[k * 128 + 64 + d];
    }
    for (int i = t; i < 384; i += 256) {
        int rr = i >> 6, k = i & 63;
        float a = gu_b1[k];
        for (int d = 0; d < 64; ++d)
            a += gu_w1[k * 128 + 64 + d] * rate_emb[rr * 64 + d];
        ws[OFF_ERC + i] = a;
    }
}

__global__ void prep2_qc(const int* __restrict__ iids, const float* __restrict__ item_emb,
                         const float* __restrict__ ws, float* __restrict__ qc) {
    int b = blockIdx.x, k = threadIdx.x;
    int iid = iids[b];
    const float* awbT = ws + OFF_AW1BT;
    const float* irow = item_emb + (size_t)iid * 64;
    float acc = 0.f;
    for (int d = 0; d < 64; ++d)
        acc = fmaf(awbT[d * 64 + k], irow[d], acc);
    qc[b * 64 + k] = acc;
}

// ---------- main: 4 INDEPENDENT waves per 256-thr block, 2 tiles per wave ----------
// r12 lesson: 1-wave workgroups cap at ~7-10 resident waves/CU (per-CU WG-slot
// limit, not LDS/VGPR). Packing 4 independent waves per WG raises waves per
// WG-slot 4x. No __syncthreads: waves share only the LDS allocation (partitioned
// per wave; b-independent tables written redundantly — benign identical races).
// __launch_bounds__(256) declares the true size; NO min-waves arg (r5/r7/r8:
// any register cap on this body => catastrophic scratch spill).
__global__ __launch_bounds__(256) void fused_main(
    const int* __restrict__ pad, const float* __restrict__ user_emb,
    const float* __restrict__ gu_b2, const float* __restrict__ att_b1,
    const float* __restrict__ att_w2, const float* __restrict__ att_b2,
    const float* __restrict__ ws, float* __restrict__ aggbuf, float* __restrict__ scbuf) {

    __shared__ __align__(16) __bf16 XH[4][32 * 64];   // per-wave hi plane (4 KB each)
    __shared__ float erc_s[6 * 65];
    __shared__ int   rid_s[4][32];
    __shared__ float mask_s[4][32];
    __shared__ float b2_s[64], aw2_s[64], ab1_s[64];
    __shared__ float qc_s[4][64];

    const int tid = threadIdx.x;
    const int w = tid >> 6;            // wave 0..3 (independent jobs)
    const int lane = tid & 63;
    const unsigned id = blockIdx.x * 4 + w;   // chunk id < B_SZ*7
    const int b = id / 7;
    const int c = id - b * 7;          // chunk 0..6
    const bool has2 = (c < 6);         // chunk 6 holds only tile 12
    const int lrow = lane & 15;
    const int lgrp = lane >> 4;
    const int lcol = lane & 15;
    const unsigned* __restrict__ bfrag = (const unsigned*)ws + OFF_BFRAG;
    const float ab2 = att_b2[0];

    __bf16* XHw  = XH[w];
    int*    ridw = rid_s[w];
    float*  mskw = mask_s[w];
    float*  qcw  = qc_s[w];

    // ---- per-wave staging (b-independent tables written redundantly by each
    //      wave BEFORE its own reads — no cross-wave dependency, no barrier) ----
    b2_s[lane]  = gu_b2[lane];
    aw2_s[lane] = att_w2[lane];
    ab1_s[lane] = att_b1[lane];
    qcw[lane]   = ws[OFF_QC + b * 64 + lane];
#pragma unroll
    for (int i = 0; i < 6; ++i) {
        int j = i * 64 + lane;
        erc_s[(j >> 6) * 65 + (j & 63)] = ws[OFF_ERC + j];
    }

    // ---- stage owned tiles: gather user_emb, bf16 cvt, swizzled LDS ----
    {
        const int dq = lane & 15;      // 4-col group
        const int rowt = lane >> 4;    // 0..3
#pragma unroll
        for (int lt = 0; lt < 2; ++lt) {
            if (lt == 0 || has2) {
                const int gt = 2 * c + lt;
#pragma unroll
                for (int p = 0; p < 4; ++p) {
                    int rr = p * 4 + rowt;         // row in tile
                    int lr = lt * 16 + rr;         // local row 0..31
                    int n  = gt * 16 + rr;         // global row
                    int uid = 0, rid = 0;
                    float4 v = make_float4(0.f, 0.f, 0.f, 0.f);
                    if (n < N_SZ) {
                        int2 pr = ((const int2*)pad)[b * N_SZ + n];
                        uid = pr.x; rid = pr.y;
                        v = *(const float4*)(user_emb + (size_t)uid * 64 + dq * 4);
                    }
                    bf16x4 hv = { (__bf16)v.x, (__bf16)v.y, (__bf16)v.z, (__bf16)v.w };
                    int g = dq >> 1;
                    int idx = lr * 64 + ((g ^ (lr & 7)) << 3) + (dq & 1) * 4;
                    *(bf16x4*)&XHw[idx] = hv;
                    if (dq == 0) {
                        ridw[lr] = (n < N_SZ) ? rid : 0;
                        mskw[lr] = (n < N_SZ && uid > 0) ? 1.f : 0.f;
                    }
                }
            }
        }
    }
    // no barrier: each wave reads only LDS it wrote; compiler orders via lgkmcnt.

    auto loadA = [&](const __bf16* P, int lt, bf16x8 A[2]) {
        int ln = lt * 16 + lrow;
        int s = ln & 7;
#pragma unroll
        for (int kt = 0; kt < 2; ++kt)
            A[kt] = *(const bf16x8*)&P[ln * 64 + (((kt * 4 + lgrp) ^ s) << 3)];
    };

#define LOAD_B(LAYER)                                                            \
    u32x4 bh[4][2], bl[4][2];                                                    \
    _Pragma("unroll")                                                            \
    for (int ct = 0; ct < 4; ++ct)                                               \
        _Pragma("unroll")                                                        \
        for (int kt = 0; kt < 2; ++kt) {                                         \
            int fb = (((LAYER) * 2 + kt) * 4 + ct) * 2;                          \
            bh[ct][kt] = *(const u32x4*)&bfrag[(fb + 0) * 256 + lane * 4];       \
            bl[ct][kt] = *(const u32x4*)&bfrag[(fb + 1) * 256 + lane * 4];       \
        }

// activations hi-only: 2 MFMAs per (ct,kt) — AH*BL (small term first), AH*BH
#define MFMA2(ACC)                                                               \
    _Pragma("unroll")                                                            \
    for (int ct = 0; ct < 4; ++ct)                                               \
        _Pragma("unroll")                                                        \
        for (int kt = 0; kt < 2; ++kt) {                                         \
            bf16x8 BH = __builtin_bit_cast(bf16x8, bh[ct][kt]);                  \
            bf16x8 BL = __builtin_bit_cast(bf16x8, bl[ct][kt]);                  \
            ACC[ct] = __builtin_amdgcn_mfma_f32_16x16x32_bf16(AH[kt], BL, ACC[ct], 0, 0, 0); \
            ACC[ct] = __builtin_amdgcn_mfma_f32_16x16x32_bf16(AH[kt], BH, ACC[ct], 0, 0, 0); \
        }

    f32x4 f_reg[2][4];   // both tiles' layer-2 outputs (exact f32 for agg)

    // ---- layer 1: h = relu(P @ W1a^T + erc[rid]) ----
    {
        LOAD_B(0)
#pragma unroll
        for (int lt = 0; lt < 2; ++lt) {
            if (lt == 0 || has2) {
                bf16x8 AH[2];
                loadA(XHw, lt, AH);
                int nr[4], ridr[4];
#pragma unroll
                for (int r = 0; r < 4; ++r) { nr[r] = lt * 16 + lgrp * 4 + r; ridr[r] = ridw[nr[r]]; }
                f32x4 acc[4];
#pragma unroll
                for (int ct = 0; ct < 4; ++ct) {
                    int k = ct * 16 + lcol;
#pragma unroll
                    for (int r = 0; r < 4; ++r) acc[ct][r] = erc_s[ridr[r] * 65 + k];
                }
                MFMA2(acc)
#pragma unroll
                for (int ct = 0; ct < 4; ++ct) {
                    int col = ct * 16 + lcol;
#pragma unroll
                    for (int r = 0; r < 4; ++r) {
                        float hv = fmaxf(acc[ct][r], 0.f);
                        int ln = nr[r];
                        int idx = ln * 64 + (((col >> 3) ^ (ln & 7)) << 3) + (col & 7);
                        XHw[idx] = (__bf16)hv;
                    }
                }
            }
        }
    }

    // ---- layer 2: f = h @ W2^T + b2 (regs; hi stored for layer 3) ----
    {
        LOAD_B(1)
#pragma unroll
        for (int lt = 0; lt < 2; ++lt) {
            if (lt == 0 || has2) {
                bf16x8 AH[2];
                loadA(XHw, lt, AH);
                f32x4 (&acc)[4] = f_reg[lt];
#pragma unroll
                for (int ct = 0; ct < 4; ++ct) {
                    float bb = b2_s[ct * 16 + lcol];
#pragma unroll
                    for (int r = 0; r < 4; ++r) acc[ct][r] = bb;
                }
                MFMA2(acc)
#pragma unroll
                for (int ct = 0; ct < 4; ++ct) {
                    int col = ct * 16 + lcol;
#pragma unroll
                    for (int r = 0; r < 4; ++r) {
                        int ln = lt * 16 + lgrp * 4 + r;
                        int idx = ln * 64 + (((col >> 3) ^ (ln & 7)) << 3) + (col & 7);
                        XHw[idx] = (__bf16)acc[ct][r];   // layer-3 A operand
                    }
                }
            }
        }
    }

    // ---- layer 3 + miu + in-register agg ----
    float aggr[4] = { 0.f, 0.f, 0.f, 0.f };
    float swave = 0.f;
    {
        LOAD_B(2)
#pragma unroll
        for (int lt = 0; lt < 2; ++lt) {
            if (lt == 0 || has2) {
                bf16x8 AH[2];
                loadA(XHw, lt, AH);
                float maskr[4];
#pragma unroll
                for (int r = 0; r < 4; ++r) maskr[r] = mskw[lt * 16 + lgrp * 4 + r];
                f32x4 acc[4];
#pragma unroll
                for (int ct = 0; ct < 4; ++ct) {
                    int k = ct * 16 + lcol;
                    float bb = ab1_s[k], qq = qcw[k];
#pragma unroll
                    for (int r = 0; r < 4; ++r) acc[ct][r] = fmaf(maskr[r], qq, bb);
                }
                MFMA2(acc)
                float pm[4] = { 0.f, 0.f, 0.f, 0.f };
#pragma unroll
                for (int ct = 0; ct < 4; ++ct) {
                    float w2v = aw2_s[ct * 16 + lcol];
#pragma unroll
                    for (int r = 0; r < 4; ++r)
                        pm[r] = fmaf(fmaxf(acc[ct][r], 0.f), w2v, pm[r]);
                }
#pragma unroll
                for (int off = 1; off <= 8; off <<= 1) {
#pragma unroll
                    for (int r = 0; r < 4; ++r) pm[r] += __shfl_xor(pm[r], off);
                }
                float miur[4];
#pragma unroll
                for (int r = 0; r < 4; ++r) {
                    miur[r] = __expf(pm[r] + ab2) * maskr[r];
                    swave += miur[r];
                }
#pragma unroll
                for (int ct = 0; ct < 4; ++ct)
#pragma unroll
                    for (int r = 0; r < 4; ++r)
                        aggr[ct] = fmaf(miur[r], f_reg[lt][ct][r], aggr[ct]);
            }
        }
    }

    // ---- reduce over lane groups, then atomic partials into ws ----
#pragma unroll
    for (int ct = 0; ct < 4; ++ct) {
        float v = aggr[ct];
        v += __shfl_xor(v, 16);
        v += __shfl_xor(v, 32);
        aggr[ct] = v;
    }
    swave += __shfl_xor(swave, 16);
    swave += __shfl_xor(swave, 32);
    if (lane < 16) {
#pragma unroll
        for (int ct = 0; ct < 4; ++ct)
            atomicAdd(&aggbuf[b * 64 + ct * 16 + lane], aggr[ct]);
    }
    if (lane == 0)
        atomicAdd(&scbuf[b], swave);
}

// ---- normalize + z = relu(agg @ agg_w^T + agg_b) ----
__global__ __launch_bounds__(256) void final_z(const float* __restrict__ aggbuf,
                                               const float* __restrict__ scbuf,
                                               const float* __restrict__ agg_w,
                                               const float* __restrict__ agg_b,
                                               float* __restrict__ out) {
    __shared__ float aws[64 * 65];
    int t = threadIdx.x;
    for (int idx = t; idx < 4096; idx += 256)
        aws[(idx >> 6) * 65 + (idx & 63)] = agg_w[idx];
    __syncthreads();
    int g = t >> 6, k = t & 63;
    for (int bi = 0; bi < 2; ++bi) {
        int b = blockIdx.x * 8 + g * 2 + bi;
        const float* arow = aggbuf + b * 64;   // wave-uniform -> s_load
        float inv = 1.f / (scbuf[b] + 1e-10f);
        float dot = 0.f;
        for (int d = 0; d < 64; ++d)
            dot = fmaf(aws[k * 65 + d], arow[d], dot);
        out[b * 64 + k] = fmaxf(fmaf(inv, dot, agg_b[k]), 0.f);
    }
}

extern "C" void kernel_launch(void* const* d_in, const int* in_sizes, int n_in,
                              void* d_out, int out_size, void* d_ws, size_t ws_size,
                              hipStream_t stream) {
    const int*   iids     = (const int*)d_in[0];
    const int*   pad      = (const int*)d_in[1];
    const float* user_emb = (const float*)d_in[2];
    const float* item_emb = (const float*)d_in[3];
    const float* rate_emb = (const float*)d_in[4];
    const float* gu_w1    = (const float*)d_in[5];
    const float* gu_b1    = (const float*)d_in[6];
    const float* gu_w2    = (const float*)d_in[7];
    const float* gu_b2    = (const float*)d_in[8];
    const float* att_w1   = (const float*)d_in[9];
    const float* att_b1   = (const float*)d_in[10];
    const float* att_w2   = (const float*)d_in[11];
    const float* att_b2   = (const float*)d_in[12];
    const float* agg_w    = (const float*)d_in[13];
    const float* agg_b    = (const float*)d_in[14];
    float* ws  = (float*)d_ws;
    float* out = (float*)d_out;

    hipLaunchKernelGGL(prep1, dim3(1), dim3(256), 0, stream,
                       gu_w1, gu_b1, gu_w2, att_w1, rate_emb, ws);
    hipLaunchKernelGGL(prep2_qc, dim3(B_SZ), dim3(64), 0, stream,
                       iids, item_emb, ws, ws + OFF_QC);
    hipMemsetAsync(ws + OFF_AGG, 0, (size_t)(B_SZ * 64 + B_SZ) * sizeof(float), stream);
    hipLaunchKernelGGL(fused_main, dim3(B_SZ * 7 / 4), dim3(256), 0, stream,
                       pad, user_emb, gu_b2, att_b1, att_w2, att_b2,
                       ws, ws + OFF_AGG, ws + OFF_SC);
    hipLaunchKernelGGL(final_z, dim3(B_SZ / 8), dim3(256), 0, stream,
                       ws + OFF_AGG, ws + OFF_SC, agg_w, agg_b, out);
}

// Round 14
// 162.330 us; speedup vs baseline: 1.2041x; 1.2041x over previous
//
#include <hip/hip_runtime.h>
#include <hip/hip_bf16.h>

#define B_SZ 4096
#define N_SZ 200

// workspace offsets (4-byte units)
#define OFF_BFRAG 0        // 12288 u32: W-fragments, 3 layers x 2kt x 4ct x 2(hi/lo) x 64 lanes x 4 u32
#define OFF_AW1BT 12288    // 4096 f32: aw1bT[d][k] = att_w1[k][64+d]  (for qc prep)
#define OFF_ERC   16384    // 384  f32: erc[r][k]
#define OFF_QC    16768    // B*64 f32: qc[b][k]
#define OFF_AGG   278912   // B*64 f32: unnormalized sum miu*f (atomic)
#define OFF_SC    541056   // B    f32: sum miu (atomic)
// total 545152 floats = 2.18 MB

typedef __attribute__((ext_vector_type(8))) __bf16 bf16x8;
typedef __attribute__((ext_vector_type(4))) __bf16 bf16x4;
typedef __attribute__((ext_vector_type(4))) float f32x4;
typedef __attribute__((ext_vector_type(4))) unsigned u32x4;

__device__ __forceinline__ void split2(float x, unsigned &hi, unsigned &lo) {
    unsigned u = __float_as_uint(x);
    hi = (u + 0x7FFFu + ((u >> 16) & 1u)) >> 16;
    float r = x - __uint_as_float(hi << 16);
    unsigned ul = __float_as_uint(r);
    lo = (ul + 0x7FFFu + ((ul >> 16) & 1u)) >> 16;
}

// ---------- prep (unchanged, proven) ----------
__global__ void prep1(const float* __restrict__ gu_w1, const float* __restrict__ gu_b1,
                      const float* __restrict__ gu_w2, const float* __restrict__ att_w1,
                      const float* __restrict__ rate_emb, float* __restrict__ ws) {
    int t = threadIdx.x;  // 1 block x 256
    unsigned* wsu = (unsigned*)ws;
    for (int i = t; i < 12288; i += 256) {
        int frag = i >> 8, within = i & 255, lane = within >> 2, r = within & 3;
        int hl = frag & 1, ct = (frag >> 1) & 3, kt = (frag >> 3) & 1, layer = frag >> 4;
        int col = ct * 16 + (lane & 15);
        int d0 = kt * 32 + 8 * (lane >> 4) + 2 * r;
        float w0, w1v;
        if (layer == 0)      { w0 = gu_w1[col * 128 + d0];  w1v = gu_w1[col * 128 + d0 + 1]; }
        else if (layer == 1) { w0 = gu_w2[col * 64 + d0];   w1v = gu_w2[col * 64 + d0 + 1]; }
        else                 { w0 = att_w1[col * 128 + d0]; w1v = att_w1[col * 128 + d0 + 1]; }
        unsigned h0, l0, h1, l1;
        split2(w0, h0, l0); split2(w1v, h1, l1);
        unsigned lo16 = hl ? l0 : h0;
        unsigned hi16 = hl ? l1 : h1;
        wsu[OFF_BFRAG + i] = lo16 | (hi16 << 16);
    }
    for (int i = t; i < 4096; i += 256) {
        int d = i >> 6, k = i & 63;
        ws[OFF_AW1BT + i] = att_w1[k * 128 + 64 + d];
    }
    for (int i = t; i < 384; i += 256) {
        int rr = i >> 6, k = i & 63;
        float a = gu_b1[k];
        for (int d = 0; d < 64; ++d)
            a += gu_w1[k * 128 + 64 + d] * rate_emb[rr * 64 + d];
        ws[OFF_ERC + i] = a;
    }
}

__global__ void prep2_qc(const int* __restrict__ iids, const float* __restrict__ item_emb,
                         const float* __restrict__ ws, float* __restrict__ qc) {
    int b = blockIdx.x, k = threadIdx.x;
    int iid = iids[b];
    const float* awbT = ws + OFF_AW1BT;
    const float* irow = item_emb + (size_t)iid * 64;
    float acc = 0.f;
    for (int d = 0; d < 64; ++d)
        acc = fmaf(awbT[d * 64 + k], irow[d], acc);
    qc[b * 64 + k] = acc;
}

// ---------- main: 1 wave per block, ONE 16-row tile per wave, ~4.8 KB LDS ----------
// Occupancy-class model (r11-r13): latency-bound, time ~ 1/floor(512/VGPR).
// Register diet vs r12: single-tile f_reg (16 regs, was 32) and per-ct B-frag
// loads (16 regs live, was 64). Target <=73 VGPR (7 waves/SIMD class).
// __launch_bounds__(64) REQUIRED (r10: default 1024-thr budget caps at 64 and
// spills ~490 B/thread); NO min-waves arg (r5/r7/r8: caps => massive spill).
__global__ __launch_bounds__(64) void fused_main(
    const int* __restrict__ pad, const float* __restrict__ user_emb,
    const float* __restrict__ gu_b2, const float* __restrict__ att_b1,
    const float* __restrict__ att_w2, const float* __restrict__ att_b2,
    const float* __restrict__ ws, float* __restrict__ aggbuf, float* __restrict__ scbuf) {

    __shared__ __align__(16) __bf16 XH[16 * 64];   // one tile, hi plane (2 KB)
    __shared__ float erc_s[6 * 65];
    __shared__ int   rid_s[16];
    __shared__ float mask_s[16];
    __shared__ float b2_s[64], aw2_s[64], ab1_s[64], qc_s[64];

    const unsigned id = blockIdx.x;    // < B_SZ*13
    const int b = id / 13;
    const int t = id - b * 13;         // tile 0..12
    const int lane = threadIdx.x;      // 0..63 (one wave)
    const int lrow = lane & 15;
    const int lgrp = lane >> 4;
    const int lcol = lane & 15;
    const unsigned* __restrict__ bfrag = (const unsigned*)ws + OFF_BFRAG;
    const float ab2 = att_b2[0];

    // ---- per-block tiny staging (single wave; LDS deps compiler-ordered) ----
    b2_s[lane]  = gu_b2[lane];
    aw2_s[lane] = att_w2[lane];
    ab1_s[lane] = att_b1[lane];
    qc_s[lane]  = ws[OFF_QC + b * 64 + lane];
#pragma unroll
    for (int i = 0; i < 6; ++i) {
        int j = i * 64 + lane;
        erc_s[(j >> 6) * 65 + (j & 63)] = ws[OFF_ERC + j];
    }

    // ---- stage the tile: gather user_emb, bf16 cvt, swizzled LDS ----
    {
        const int dq = lane & 15;      // 4-col group
        const int rowt = lane >> 4;    // 0..3
#pragma unroll
        for (int p = 0; p < 4; ++p) {
            int lr = p * 4 + rowt;             // local row 0..15
            int n  = t * 16 + lr;              // global row
            int uid = 0, rid = 0;
            float4 v = make_float4(0.f, 0.f, 0.f, 0.f);
            if (n < N_SZ) {
                int2 pr = ((const int2*)pad)[b * N_SZ + n];
                uid = pr.x; rid = pr.y;
                v = *(const float4*)(user_emb + (size_t)uid * 64 + dq * 4);
            }
            bf16x4 hv = { (__bf16)v.x, (__bf16)v.y, (__bf16)v.z, (__bf16)v.w };
            int g = dq >> 1;
            int idx = lr * 64 + ((g ^ (lr & 7)) << 3) + (dq & 1) * 4;
            *(bf16x4*)&XH[idx] = hv;
            if (dq == 0) {
                rid_s[lr]  = (n < N_SZ) ? rid : 0;
                mask_s[lr] = (n < N_SZ && uid > 0) ? 1.f : 0.f;
            }
        }
    }
    // no barrier: single wave; per-wave DS ops are in-order (lgkmcnt-waited).

    // A-frag: row = lrow, k = kt*32+8*lgrp+e -> one swizzled granule per kt
    auto loadA = [&](bf16x8 A[2]) {
        int s = lrow & 7;
#pragma unroll
        for (int kt = 0; kt < 2; ++kt)
            A[kt] = *(const bf16x8*)&XH[lrow * 64 + (((kt * 4 + lgrp) ^ s) << 3)];
    };

// Per-ct B-frag loads (16 VGPRs live) + 4 chained MFMAs into ACC[ct].
// Weights keep hi/lo split; activations hi-only (r12 numerics, absmax 1.95e-3).
#define LAYER_MFMA(LAYER_ID, ACC, AHARR)                                         \
    _Pragma("unroll")                                                            \
    for (int ct = 0; ct < 4; ++ct) {                                             \
        const unsigned* fb = &bfrag[((((LAYER_ID) * 2 + 0) * 4 + ct) * 2) * 256 + lane * 4]; \
        u32x4 bh0 = *(const u32x4*)(fb + 0 * 256);                               \
        u32x4 bl0 = *(const u32x4*)(fb + 1 * 256);                               \
        u32x4 bh1 = *(const u32x4*)(fb + 8 * 256);                               \
        u32x4 bl1 = *(const u32x4*)(fb + 9 * 256);                               \
        ACC[ct] = __builtin_amdgcn_mfma_f32_16x16x32_bf16(AHARR[0], __builtin_bit_cast(bf16x8, bl0), ACC[ct], 0, 0, 0); \
        ACC[ct] = __builtin_amdgcn_mfma_f32_16x16x32_bf16(AHARR[0], __builtin_bit_cast(bf16x8, bh0), ACC[ct], 0, 0, 0); \
        ACC[ct] = __builtin_amdgcn_mfma_f32_16x16x32_bf16(AHARR[1], __builtin_bit_cast(bf16x8, bl1), ACC[ct], 0, 0, 0); \
        ACC[ct] = __builtin_amdgcn_mfma_f32_16x16x32_bf16(AHARR[1], __builtin_bit_cast(bf16x8, bh1), ACC[ct], 0, 0, 0); \
    }

    // ---- layer 1: h = relu(P @ W1a^T + erc[rid]) ----
    {
        bf16x8 AH[2];
        loadA(AH);
        int ridr[4];
#pragma unroll
        for (int r = 0; r < 4; ++r) ridr[r] = rid_s[lgrp * 4 + r];
        f32x4 acc[4];
#pragma unroll
        for (int ct = 0; ct < 4; ++ct) {
            int k = ct * 16 + lcol;
#pragma unroll
            for (int r = 0; r < 4; ++r) acc[ct][r] = erc_s[ridr[r] * 65 + k];
        }
        LAYER_MFMA(0, acc, AH)
#pragma unroll
        for (int ct = 0; ct < 4; ++ct) {
            int col = ct * 16 + lcol;
#pragma unroll
            for (int r = 0; r < 4; ++r) {
                float hv = fmaxf(acc[ct][r], 0.f);
                int ln = lgrp * 4 + r;
                int idx = ln * 64 + (((col >> 3) ^ (ln & 7)) << 3) + (col & 7);
                XH[idx] = (__bf16)hv;
            }
        }
    }

    // ---- layer 2: f = h @ W2^T + b2 (f32 in regs; hi stored for layer 3) ----
    f32x4 f_reg[4];
    {
        bf16x8 AH[2];
        loadA(AH);
#pragma unroll
        for (int ct = 0; ct < 4; ++ct) {
            float bb = b2_s[ct * 16 + lcol];
#pragma unroll
            for (int r = 0; r < 4; ++r) f_reg[ct][r] = bb;
        }
        LAYER_MFMA(1, f_reg, AH)
#pragma unroll
        for (int ct = 0; ct < 4; ++ct) {
            int col = ct * 16 + lcol;
#pragma unroll
            for (int r = 0; r < 4; ++r) {
                int ln = lgrp * 4 + r;
                int idx = ln * 64 + (((col >> 3) ^ (ln & 7)) << 3) + (col & 7);
                XH[idx] = (__bf16)f_reg[ct][r];   // layer-3 A operand
            }
        }
    }

    // ---- layer 3 + miu + in-register agg partial ----
    float aggr[4];
    float swave = 0.f;
    {
        bf16x8 AH[2];
        loadA(AH);
        float maskr[4];
#pragma unroll
        for (int r = 0; r < 4; ++r) maskr[r] = mask_s[lgrp * 4 + r];
        f32x4 acc[4];
#pragma unroll
        for (int ct = 0; ct < 4; ++ct) {
            int k = ct * 16 + lcol;
            float bb = ab1_s[k], qq = qc_s[k];
#pragma unroll
            for (int r = 0; r < 4; ++r) acc[ct][r] = fmaf(maskr[r], qq, bb);
        }
        LAYER_MFMA(2, acc, AH)
        float pm[4] = { 0.f, 0.f, 0.f, 0.f };
#pragma unroll
        for (int ct = 0; ct < 4; ++ct) {
            float w2v = aw2_s[ct * 16 + lcol];
#pragma unroll
            for (int r = 0; r < 4; ++r)
                pm[r] = fmaf(fmaxf(acc[ct][r], 0.f), w2v, pm[r]);
        }
#pragma unroll
        for (int off = 1; off <= 8; off <<= 1) {
#pragma unroll
            for (int r = 0; r < 4; ++r) pm[r] += __shfl_xor(pm[r], off);
        }
        float miur[4];
#pragma unroll
        for (int r = 0; r < 4; ++r) {
            miur[r] = __expf(pm[r] + ab2) * maskr[r];
            swave += miur[r];
        }
#pragma unroll
        for (int ct = 0; ct < 4; ++ct) {
            float a = 0.f;
#pragma unroll
            for (int r = 0; r < 4; ++r)
                a = fmaf(miur[r], f_reg[ct][r], a);
            aggr[ct] = a;
        }
    }

    // ---- reduce over lane groups, then atomic partials into ws ----
#pragma unroll
    for (int ct = 0; ct < 4; ++ct) {
        float v = aggr[ct];
        v += __shfl_xor(v, 16);
        v += __shfl_xor(v, 32);
        aggr[ct] = v;
    }
    swave += __shfl_xor(swave, 16);
    swave += __shfl_xor(swave, 32);
    if (lane < 16) {
#pragma unroll
        for (int ct = 0; ct < 4; ++ct)
            atomicAdd(&aggbuf[b * 64 + ct * 16 + lane], aggr[ct]);
    }
    if (lane == 0)
        atomicAdd(&scbuf[b], swave);
}

// ---- normalize + z = relu(agg @ agg_w^T + agg_b) ----
__global__ __launch_bounds__(256) void final_z(const float* __restrict__ aggbuf,
                                               const float* __restrict__ scbuf,
                                               const float* __restrict__ agg_w,
                                               const float* __restrict__ agg_b,
                                               float* __restrict__ out) {
    __shared__ float aws[64 * 65];
    int t = threadIdx.x;
    for (int idx = t; idx < 4096; idx += 256)
        aws[(idx >> 6) * 65 + (idx & 63)] = agg_w[idx];
    __syncthreads();
    int g = t >> 6, k = t & 63;
    for (int bi = 0; bi < 2; ++bi) {
        int b = blockIdx.x * 8 + g * 2 + bi;
        const float* arow = aggbuf + b * 64;   // wave-uniform -> s_load
        float inv = 1.f / (scbuf[b] + 1e-10f);
        float dot = 0.f;
        for (int d = 0; d < 64; ++d)
            dot = fmaf(aws[k * 65 + d], arow[d], dot);
        out[b * 64 + k] = fmaxf(fmaf(inv, dot, agg_b[k]), 0.f);
    }
}

extern "C" void kernel_launch(void* const* d_in, const int* in_sizes, int n_in,
                              void* d_out, int out_size, void* d_ws, size_t ws_size,
                              hipStream_t stream) {
    const int*   iids     = (const int*)d_in[0];
    const int*   pad      = (const int*)d_in[1];
    const float* user_emb = (const float*)d_in[2];
    const float* item_emb = (const float*)d_in[3];
    const float* rate_emb = (const float*)d_in[4];
    const float* gu_w1    = (const float*)d_in[5];
    const float* gu_b1    = (const float*)d_in[6];
    const float* gu_w2    = (const float*)d_in[7];
    const float* gu_b2    = (const float*)d_in[8];
    const float* att_w1   = (const float*)d_in[9];
    const float* att_b1   = (const float*)d_in[10];
    const float* att_w2   = (const float*)d_in[11];
    const float* att_b2   = (const float*)d_in[12];
    const float* agg_w    = (const float*)d_in[13];
    const float* agg_b    = (const float*)d_in[14];
    float* ws  = (float*)d_ws;
    float* out = (float*)d_out;

    hipLaunchKernelGGL(prep1, dim3(1), dim3(256), 0, stream,
                       gu_w1, gu_b1, gu_w2, att_w1, rate_emb, ws);
    hipLaunchKernelGGL(prep2_qc, dim3(B_SZ), dim3(64), 0, stream,
                       iids, item_emb, ws, ws + OFF_QC);
    hipMemsetAsync(ws + OFF_AGG, 0, (size_t)(B_SZ * 64 + B_SZ) * sizeof(float), stream);
    hipLaunchKernelGGL(fused_main, dim3(B_SZ * 13), dim3(64), 0, stream,
                       pad, user_emb, gu_b2, att_b1, att_w2, att_b2,
                       ws, ws + OFF_AGG, ws + OFF_SC);
    hipLaunchKernelGGL(final_z, dim3(B_SZ / 8), dim3(256), 0, stream,
                       ws + OFF_AGG, ws + OFF_SC, agg_w, agg_b, out);
}

// Round 15
// 133.566 us; speedup vs baseline: 1.4634x; 1.2153x over previous
//
#include <hip/hip_runtime.h>
#include <hip/hip_bf16.h>

#define B_SZ 4096
#define N_SZ 200

// workspace offsets (4-byte units)
#define OFF_BFRAG 0        // 12288 u32: W-fragments, 3 layers x 2kt x 4ct x 2(hi/lo) x 64 lanes x 4 u32
#define OFF_AW1BT 12288    // 4096 f32: aw1bT[d][k] = att_w1[k][64+d]  (for qc prep)
#define OFF_ERC   16384    // 384  f32: erc[r][k]
#define OFF_QC    16768    // B*64 f32: qc[b][k]
#define OFF_AGG   278912   // B*64 f32: unnormalized sum miu*f (atomic)
#define OFF_SC    541056   // B    f32: sum miu (atomic)
// total 545152 floats = 2.18 MB

typedef __attribute__((ext_vector_type(8))) __bf16 bf16x8;
typedef __attribute__((ext_vector_type(4))) __bf16 bf16x4;
typedef __attribute__((ext_vector_type(4))) float f32x4;
typedef __attribute__((ext_vector_type(4))) unsigned u32x4;

__device__ __forceinline__ void split2(float x, unsigned &hi, unsigned &lo) {
    unsigned u = __float_as_uint(x);
    hi = (u + 0x7FFFu + ((u >> 16) & 1u)) >> 16;
    float r = x - __uint_as_float(hi << 16);
    unsigned ul = __float_as_uint(r);
    lo = (ul + 0x7FFFu + ((ul >> 16) & 1u)) >> 16;
}

// ---------- prep (unchanged, proven; lo rows now unused by fused_main) ----------
__global__ void prep1(const float* __restrict__ gu_w1, const float* __restrict__ gu_b1,
                      const float* __restrict__ gu_w2, const float* __restrict__ att_w1,
                      const float* __restrict__ rate_emb, float* __restrict__ ws) {
    int t = threadIdx.x;  // 1 block x 256
    unsigned* wsu = (unsigned*)ws;
    for (int i = t; i < 12288; i += 256) {
        int frag = i >> 8, within = i & 255, lane = within >> 2, r = within & 3;
        int hl = frag & 1, ct = (frag >> 1) & 3, kt = (frag >> 3) & 1, layer = frag >> 4;
        int col = ct * 16 + (lane & 15);
        int d0 = kt * 32 + 8 * (lane >> 4) + 2 * r;
        float w0, w1v;
        if (layer == 0)      { w0 = gu_w1[col * 128 + d0];  w1v = gu_w1[col * 128 + d0 + 1]; }
        else if (layer == 1) { w0 = gu_w2[col * 64 + d0];   w1v = gu_w2[col * 64 + d0 + 1]; }
        else                 { w0 = att_w1[col * 128 + d0]; w1v = att_w1[col * 128 + d0 + 1]; }
        unsigned h0, l0, h1, l1;
        split2(w0, h0, l0); split2(w1v, h1, l1);
        unsigned lo16 = hl ? l0 : h0;
        unsigned hi16 = hl ? l1 : h1;
        wsu[OFF_BFRAG + i] = lo16 | (hi16 << 16);
    }
    for (int i = t; i < 4096; i += 256) {
        int d = i >> 6, k = i & 63;
        ws[OFF_AW1BT + i] = att_w1[k * 128 + 64 + d];
    }
    for (int i = t; i < 384; i += 256) {
        int rr = i >> 6, k = i & 63;
        float a = gu_b1[k];
        for (int d = 0; d < 64; ++d)
            a += gu_w1[k * 128 + 64 + d] * rate_emb[rr * 64 + d];
        ws[OFF_ERC + i] = a;
    }
}

__global__ void prep2_qc(const int* __restrict__ iids, const float* __restrict__ item_emb,
                         const float* __restrict__ ws, float* __restrict__ qc) {
    int b = blockIdx.x, k = threadIdx.x;
    int iid = iids[b];
    const float* awbT = ws + OFF_AW1BT;
    const float* irow = item_emb + (size_t)iid * 64;
    float acc = 0.f;
    for (int d = 0; d < 64; ++d)
        acc = fmaf(awbT[d * 64 + k], irow[d], acc);
    qc[b * 64 + k] = acc;
}

// ---------- main: 1 wave per block, ONE 16-row tile, bf16 weights (hi only) ----------
// r14 post-mortem: occupancy no longer binds (43%); residual cost = W-frag L2
// traffic (2.6 GB) + 4-deep MFMA chains. r15: weights hi-only -> MFMA count,
// W L2 traffic, and B-frag regs all halve. Predicted absmax 2-4e-3 (< 6.29e-3).
// __launch_bounds__(64) REQUIRED (r10 spill lesson); NO min-waves arg (r5/r7/r8).
__global__ __launch_bounds__(64) void fused_main(
    const int* __restrict__ pad, const float* __restrict__ user_emb,
    const float* __restrict__ gu_b2, const float* __restrict__ att_b1,
    const float* __restrict__ att_w2, const float* __restrict__ att_b2,
    const float* __restrict__ ws, float* __restrict__ aggbuf, float* __restrict__ scbuf) {

    __shared__ __align__(16) __bf16 XH[16 * 64];   // one tile, hi plane (2 KB)
    __shared__ float erc_s[6 * 65];
    __shared__ int   rid_s[16];
    __shared__ float mask_s[16];
    __shared__ float b2_s[64], aw2_s[64], ab1_s[64], qc_s[64];

    const unsigned id = blockIdx.x;    // < B_SZ*13
    const int b = id / 13;
    const int t = id - b * 13;         // tile 0..12
    const int lane = threadIdx.x;      // 0..63 (one wave)
    const int lrow = lane & 15;
    const int lgrp = lane >> 4;
    const int lcol = lane & 15;
    const unsigned* __restrict__ bfrag = (const unsigned*)ws + OFF_BFRAG;
    const float ab2 = att_b2[0];

    // ---- per-block tiny staging (single wave; LDS deps compiler-ordered) ----
    b2_s[lane]  = gu_b2[lane];
    aw2_s[lane] = att_w2[lane];
    ab1_s[lane] = att_b1[lane];
    qc_s[lane]  = ws[OFF_QC + b * 64 + lane];
#pragma unroll
    for (int i = 0; i < 6; ++i) {
        int j = i * 64 + lane;
        erc_s[(j >> 6) * 65 + (j & 63)] = ws[OFF_ERC + j];
    }

    // ---- stage the tile: gather user_emb, bf16 cvt, swizzled LDS ----
    {
        const int dq = lane & 15;      // 4-col group
        const int rowt = lane >> 4;    // 0..3
#pragma unroll
        for (int p = 0; p < 4; ++p) {
            int lr = p * 4 + rowt;             // local row 0..15
            int n  = t * 16 + lr;              // global row
            int uid = 0, rid = 0;
            float4 v = make_float4(0.f, 0.f, 0.f, 0.f);
            if (n < N_SZ) {
                int2 pr = ((const int2*)pad)[b * N_SZ + n];
                uid = pr.x; rid = pr.y;
                v = *(const float4*)(user_emb + (size_t)uid * 64 + dq * 4);
            }
            bf16x4 hv = { (__bf16)v.x, (__bf16)v.y, (__bf16)v.z, (__bf16)v.w };
            int g = dq >> 1;
            int idx = lr * 64 + ((g ^ (lr & 7)) << 3) + (dq & 1) * 4;
            *(bf16x4*)&XH[idx] = hv;
            if (dq == 0) {
                rid_s[lr]  = (n < N_SZ) ? rid : 0;
                mask_s[lr] = (n < N_SZ && uid > 0) ? 1.f : 0.f;
            }
        }
    }
    // no barrier: single wave; per-wave DS ops are in-order (lgkmcnt-waited).

    // A-frag: row = lrow, k = kt*32+8*lgrp+e -> one swizzled granule per kt
    auto loadA = [&](bf16x8 A[2]) {
        int s = lrow & 7;
#pragma unroll
        for (int kt = 0; kt < 2; ++kt)
            A[kt] = *(const bf16x8*)&XH[lrow * 64 + (((kt * 4 + lgrp) ^ s) << 3)];
    };

// Weights hi-only: per ct load 2 hi-frags (kt=0,1), 2 chained MFMAs into ACC[ct].
#define LAYER_MFMA(LAYER_ID, ACC, AHARR)                                         \
    _Pragma("unroll")                                                            \
    for (int ct = 0; ct < 4; ++ct) {                                             \
        const unsigned* fb = &bfrag[((((LAYER_ID) * 2 + 0) * 4 + ct) * 2) * 256 + lane * 4]; \
        u32x4 bh0 = *(const u32x4*)(fb + 0 * 256);                               \
        u32x4 bh1 = *(const u32x4*)(fb + 8 * 256);                               \
        ACC[ct] = __builtin_amdgcn_mfma_f32_16x16x32_bf16(AHARR[0], __builtin_bit_cast(bf16x8, bh0), ACC[ct], 0, 0, 0); \
        ACC[ct] = __builtin_amdgcn_mfma_f32_16x16x32_bf16(AHARR[1], __builtin_bit_cast(bf16x8, bh1), ACC[ct], 0, 0, 0); \
    }

    // ---- layer 1: h = relu(P @ W1a^T + erc[rid]) ----
    {
        bf16x8 AH[2];
        loadA(AH);
        int ridr[4];
#pragma unroll
        for (int r = 0; r < 4; ++r) ridr[r] = rid_s[lgrp * 4 + r];
        f32x4 acc[4];
#pragma unroll
        for (int ct = 0; ct < 4; ++ct) {
            int k = ct * 16 + lcol;
#pragma unroll
            for (int r = 0; r < 4; ++r) acc[ct][r] = erc_s[ridr[r] * 65 + k];
        }
        LAYER_MFMA(0, acc, AH)
#pragma unroll
        for (int ct = 0; ct < 4; ++ct) {
            int col = ct * 16 + lcol;
#pragma unroll
            for (int r = 0; r < 4; ++r) {
                float hv = fmaxf(acc[ct][r], 0.f);
                int ln = lgrp * 4 + r;
                int idx = ln * 64 + (((col >> 3) ^ (ln & 7)) << 3) + (col & 7);
                XH[idx] = (__bf16)hv;
            }
        }
    }

    // ---- layer 2: f = h @ W2^T + b2 (f32 in regs; hi stored for layer 3) ----
    f32x4 f_reg[4];
    {
        bf16x8 AH[2];
        loadA(AH);
#pragma unroll
        for (int ct = 0; ct < 4; ++ct) {
            float bb = b2_s[ct * 16 + lcol];
#pragma unroll
            for (int r = 0; r < 4; ++r) f_reg[ct][r] = bb;
        }
        LAYER_MFMA(1, f_reg, AH)
#pragma unroll
        for (int ct = 0; ct < 4; ++ct) {
            int col = ct * 16 + lcol;
#pragma unroll
            for (int r = 0; r < 4; ++r) {
                int ln = lgrp * 4 + r;
                int idx = ln * 64 + (((col >> 3) ^ (ln & 7)) << 3) + (col & 7);
                XH[idx] = (__bf16)f_reg[ct][r];   // layer-3 A operand
            }
        }
    }

    // ---- layer 3 + miu + in-register agg partial ----
    float aggr[4];
    float swave = 0.f;
    {
        bf16x8 AH[2];
        loadA(AH);
        float maskr[4];
#pragma unroll
        for (int r = 0; r < 4; ++r) maskr[r] = mask_s[lgrp * 4 + r];
        f32x4 acc[4];
#pragma unroll
        for (int ct = 0; ct < 4; ++ct) {
            int k = ct * 16 + lcol;
            float bb = ab1_s[k], qq = qc_s[k];
#pragma unroll
            for (int r = 0; r < 4; ++r) acc[ct][r] = fmaf(maskr[r], qq, bb);
        }
        LAYER_MFMA(2, acc, AH)
        float pm[4] = { 0.f, 0.f, 0.f, 0.f };
#pragma unroll
        for (int ct = 0; ct < 4; ++ct) {
            float w2v = aw2_s[ct * 16 + lcol];
#pragma unroll
            for (int r = 0; r < 4; ++r)
                pm[r] = fmaf(fmaxf(acc[ct][r], 0.f), w2v, pm[r]);
        }
#pragma unroll
        for (int off = 1; off <= 8; off <<= 1) {
#pragma unroll
            for (int r = 0; r < 4; ++r) pm[r] += __shfl_xor(pm[r], off);
        }
        float miur[4];
#pragma unroll
        for (int r = 0; r < 4; ++r) {
            miur[r] = __expf(pm[r] + ab2) * maskr[r];
            swave += miur[r];
        }
#pragma unroll
        for (int ct = 0; ct < 4; ++ct) {
            float a = 0.f;
#pragma unroll
            for (int r = 0; r < 4; ++r)
                a = fmaf(miur[r], f_reg[ct][r], a);
            aggr[ct] = a;
        }
    }

    // ---- reduce over lane groups, then atomic partials into ws ----
#pragma unroll
    for (int ct = 0; ct < 4; ++ct) {
        float v = aggr[ct];
        v += __shfl_xor(v, 16);
        v += __shfl_xor(v, 32);
        aggr[ct] = v;
    }
    swave += __shfl_xor(swave, 16);
    swave += __shfl_xor(swave, 32);
    if (lane < 16) {
#pragma unroll
        for (int ct = 0; ct < 4; ++ct)
            atomicAdd(&aggbuf[b * 64 + ct * 16 + lane], aggr[ct]);
    }
    if (lane == 0)
        atomicAdd(&scbuf[b], swave);
}

// ---- normalize + z = relu(agg @ agg_w^T + agg_b) ----
__global__ __launch_bounds__(256) void final_z(const float* __restrict__ aggbuf,
                                               const float* __restrict__ scbuf,
                                               const float* __restrict__ agg_w,
                                               const float* __restrict__ agg_b,
                                               float* __restrict__ out) {
    __shared__ float aws[64 * 65];
    int t = threadIdx.x;
    for (int idx = t; idx < 4096; idx += 256)
        aws[(idx >> 6) * 65 + (idx & 63)] = agg_w[idx];
    __syncthreads();
    int g = t >> 6, k = t & 63;
    for (int bi = 0; bi < 2; ++bi) {
        int b = blockIdx.x * 8 + g * 2 + bi;
        const float* arow = aggbuf + b * 64;   // wave-uniform -> s_load
        float inv = 1.f / (scbuf[b] + 1e-10f);
        float dot = 0.f;
        for (int d = 0; d < 64; ++d)
            dot = fmaf(aws[k * 65 + d], arow[d], dot);
        out[b * 64 + k] = fmaxf(fmaf(inv, dot, agg_b[k]), 0.f);
    }
}

extern "C" void kernel_launch(void* const* d_in, const int* in_sizes, int n_in,
                              void* d_out, int out_size, void* d_ws, size_t ws_size,
                              hipStream_t stream) {
    const int*   iids     = (const int*)d_in[0];
    const int*   pad      = (const int*)d_in[1];
    const float* user_emb = (const float*)d_in[2];
    const float* item_emb = (const float*)d_in[3];
    const float* rate_emb = (const float*)d_in[4];
    const float* gu_w1    = (const float*)d_in[5];
    const float* gu_b1    = (const float*)d_in[6];
    const float* gu_w2    = (const float*)d_in[7];
    const float* gu_b2    = (const float*)d_in[8];
    const float* att_w1   = (const float*)d_in[9];
    const float* att_b1   = (const float*)d_in[10];
    const float* att_w2   = (const float*)d_in[11];
    const float* att_b2   = (const float*)d_in[12];
    const float* agg_w    = (const float*)d_in[13];
    const float* agg_b    = (const float*)d_in[14];
    float* ws  = (float*)d_ws;
    float* out = (float*)d_out;

    hipLaunchKernelGGL(prep1, dim3(1), dim3(256), 0, stream,
                       gu_w1, gu_b1, gu_w2, att_w1, rate_emb, ws);
    hipLaunchKernelGGL(prep2_qc, dim3(B_SZ), dim3(64), 0, stream,
                       iids, item_emb, ws, ws + OFF_QC);
    hipMemsetAsync(ws + OFF_AGG, 0, (size_t)(B_SZ * 64 + B_SZ) * sizeof(float), stream);
    hipLaunchKernelGGL(fused_main, dim3(B_SZ * 13), dim3(64), 0, stream,
                       pad, user_emb, gu_b2, att_b1, att_w2, att_b2,
                       ws, ws + OFF_AGG, ws + OFF_SC);
    hipLaunchKernelGGL(final_z, dim3(B_SZ / 8), dim3(256), 0, stream,
                       ws + OFF_AGG, ws + OFF_SC, agg_w, agg_b, out);
}